// Round 8
// baseline (148.249 us; speedup 1.0000x reference)
//
#include <hip/hip_runtime.h>
#include <math.h>

#define TPB 1024
#define HTPB 256
#define NPIX 4096
#define NJ 17
#define NL 16
static constexpr float kBeta = 100.0f;
static constexpr float S2H = 0.70710678118654752f;

// output layout (floats): kps(544) | comb_v(768) | comb_p(512) | fields_new(3145728) | hms_new(1114112)
#define O_KPS 0
#define O_CV 544
#define O_CP 1312
#define O_FN 1824
#define O_HM 3147552
// workspace layout (floats)
#define W_FDS 0               // 256*4096
#define W_W1 1049376          // 16384 cplx
#define W_W2 1082144          // 16384 cplx

__device__ __constant__ int c_P0[16] = {0,1,2,0,4,5,0,7,8,9,8,11,12,8,14,15};
__device__ __constant__ int c_P1[16] = {1,2,3,4,5,6,7,8,9,10,11,12,13,14,15,16};
__device__ __constant__ int c_proxL[17] = {6,1,2,-1,4,5,-1,7,13,9,-1,11,12,-1,14,15,-1};
__device__ __constant__ int c_distL[17] = {-1,0,1,2,3,4,5,6,7,8,9,10,11,12,13,14,15};

using cplx = float2;
__device__ inline cplx cadd(cplx a, cplx b){ return {a.x+b.x, a.y+b.y}; }
__device__ inline cplx csub(cplx a, cplx b){ return {a.x-b.x, a.y-b.y}; }
__device__ inline cplx cmul(cplx a, cplx w){ return {a.x*w.x - a.y*w.y, a.x*w.y + a.y*w.x}; }
__device__ inline cplx cmulc(cplx a, cplx w){ return {a.x*w.x + a.y*w.y, a.y*w.x - a.x*w.y}; }

// intra-wave LDS sync: wave is lockstep; lgkmcnt(0) drains this wave's own ds ops.
__device__ inline void wsync(){
  asm volatile("s_waitcnt lgkmcnt(0)" ::: "memory");
}

// w_128^{br3(p)} and w_16^{br3(p)}, br3 = {0,4,2,6,1,5,3,7}
__device__ __constant__ float2 W128BR[8] = {
  {1.f,0.f},
  {0.98078528040323044913f,-0.19509032201612826785f},
  {0.99518472667219688624f,-0.09801714032956060199f},
  {0.95694033573220886494f,-0.29028467725446236764f},
  {0.99879545620517239271f,-0.04906767432741801425f},
  {0.97003125319454399260f,-0.24298017990326388995f},
  {0.98917650996478097345f,-0.14673047445536175166f},
  {0.94154406518302077841f,-0.33688985339222005069f}
};
__device__ __constant__ float2 W16BR[8] = {
  {1.f,0.f},
  {0.f,-1.f},
  {0.70710678118654752440f,-0.70710678118654752440f},
  {-0.70710678118654752440f,-0.70710678118654752440f},
  {0.92387953251128675613f,-0.38268343236508977173f},
  {-0.38268343236508977173f,-0.92387953251128675613f},
  {0.38268343236508977173f,-0.92387953251128675613f},
  {-0.92387953251128675613f,-0.38268343236508977173f}
};

// -------- 8-point DFT (radix-2 DIF, output bit-reversed); inverse = exact inverse ----
__device__ inline void bf8_tail(cplx t0, cplx t1, cplx t2, cplx t3,
                                cplx t4, cplx t5, cplx t6, cplx t7, cplx x[8]){
  cplx u0=cadd(t0,t2), u2=csub(t0,t2);
  cplx u1=cadd(t1,t3), d13=csub(t1,t3);
  cplx u3={d13.y,-d13.x};
  cplx u4=cadd(t4,t6), u6=csub(t4,t6);
  cplx u5=cadd(t5,t7), d57=csub(t5,t7);
  cplx u7={d57.y,-d57.x};
  x[0]=cadd(u0,u1); x[1]=csub(u0,u1);
  x[2]=cadd(u2,u3); x[3]=csub(u2,u3);
  x[4]=cadd(u4,u5); x[5]=csub(u4,u5);
  x[6]=cadd(u6,u7); x[7]=csub(u6,u7);
}
__device__ inline void bf8_fwd(cplx x[8]){
  cplx t0=cadd(x[0],x[4]), d4=csub(x[0],x[4]);
  cplx t1=cadd(x[1],x[5]), d5=csub(x[1],x[5]);
  cplx t2=cadd(x[2],x[6]), d6=csub(x[2],x[6]);
  cplx t3=cadd(x[3],x[7]), d7=csub(x[3],x[7]);
  cplx t5={S2H*(d5.x+d5.y), S2H*(d5.y-d5.x)};
  cplx t6={d6.y,-d6.x};
  cplx t7={S2H*(d7.y-d7.x), -S2H*(d7.x+d7.y)};
  bf8_tail(t0,t1,t2,t3,d4,t5,t6,t7,x);
}
__device__ inline void bf8_fwd_z(cplx x[8]){   // x[4..7] == 0 implicitly
  cplx t5={S2H*(x[1].x+x[1].y), S2H*(x[1].y-x[1].x)};
  cplx t6={x[2].y,-x[2].x};
  cplx t7={S2H*(x[3].y-x[3].x), -S2H*(x[3].x+x[3].y)};
  bf8_tail(x[0],x[1],x[2],x[3],x[0],t5,t6,t7,x);
}
__device__ inline void bf8_inv(cplx y[8]){
  cplx u0=cadd(y[0],y[1]), u1=csub(y[0],y[1]);
  cplx u2=cadd(y[2],y[3]), u3=csub(y[2],y[3]);
  cplx u4=cadd(y[4],y[5]), u5=csub(y[4],y[5]);
  cplx u6=cadd(y[6],y[7]), u7=csub(y[6],y[7]);
  cplx t0=cadd(u0,u2), t2=csub(u0,u2);
  cplx iu3={-u3.y,u3.x};
  cplx t1=cadd(u1,iu3), t3=csub(u1,iu3);
  cplx t4=cadd(u4,u6), t6=csub(u4,u6);
  cplx iu7={-u7.y,u7.x};
  cplx t5=cadd(u5,iu7), t7=csub(u5,iu7);
  y[0]=cadd(t0,t4); y[4]=csub(t0,t4);
  cplx w5={S2H*(t5.x-t5.y), S2H*(t5.x+t5.y)};
  y[1]=cadd(t1,w5); y[5]=csub(t1,w5);
  cplx w6={-t6.y,t6.x};
  y[2]=cadd(t2,w6); y[6]=csub(t2,w6);
  cplx w7={-S2H*(t7.x+t7.y), S2H*(t7.x-t7.y)};
  y[3]=cadd(t3,w7); y[7]=csub(t3,w7);
}

// -------- 16-point DFT in registers; inverse = exact inverse ----------------
__device__ inline void fft16_fwd(cplx z[16]){
  cplx e[8], o[8];
  #pragma unroll
  for (int t=0;t<8;t++){ e[t]=z[2*t]; o[t]=z[2*t+1]; }
  bf8_fwd(e); bf8_fwd(o);
  #pragma unroll
  for (int p=0;p<8;p++){
    cplx vo = cmul(o[p], W16BR[p]);
    z[2*p]   = cadd(e[p], vo);
    z[2*p+1] = csub(e[p], vo);
  }
}
__device__ inline void fft16_inv(cplx z[16]){
  cplx e[8], o[8];
  #pragma unroll
  for (int p=0;p<8;p++){
    cplx a=z[2*p], b=z[2*p+1];
    e[p] = cadd(a,b);
    o[p] = cmulc(csub(a,b), W16BR[p]);
  }
  bf8_inv(e); bf8_inv(o);
  #pragma unroll
  for (int t=0;t<8;t++){ z[2*t]=e[t]; z[2*t+1]=o[t]; }
}

// A[p] = w_128^{j*br3(p)} via chain from TW[j]
__device__ inline void twchainA(const cplx* TW, int j, cplx A[8]){
  cplx W1 = TW[j];
  cplx W2 = cmul(W1,W1);
  cplx W4 = cmul(W2,W2);
  cplx W6 = cmul(W4,W2);
  A[0] = {1.f,0.f}; A[1] = W4; A[2] = W2; A[3] = W6;
  A[4] = W1; A[5] = cmul(W4,W1); A[6] = cmul(W2,W1); A[7] = cmul(W6,W1);
}

// physical f4-slot for (row y, slot m). XOR swizzle: conflict-free for all passes.
__device__ inline int PH(int y, int m){
  return (y<<6) | ((m ^ ((y&7)*9) ^ ((y>>3)&7) ^ (((y>>4)&1)<<2)) & 63);
}

// ---------------- wave-local FFT passes -------------------------------------------------
// bias: uniform value subtracted from real parts on load (conv1 mean-centering, folded in)
template<bool ZT>
__device__ inline void row_s1_f(float4* S4, const cplx* TW, int L, int m, float bias){
  cplx xe[8], xo[8];
  #pragma unroll
  for (int t=0; t<(ZT?4:8); t++){
    float4 v = S4[PH(L, m+8*t)];
    xe[t]={v.x-bias,v.y}; xo[t]={v.z-bias,v.w};
  }
  if (ZT){ bf8_fwd_z(xe); bf8_fwd_z(xo); } else { bf8_fwd(xe); bf8_fwd(xo); }
  cplx A[8]; twchainA(TW, 2*m, A);
  #pragma unroll
  for (int p=0;p<8;p++){
    cplx B = cmul(A[p], W128BR[p]);
    cplx ve = cmul(xe[p], A[p]);
    cplx vo = cmul(xo[p], B);
    S4[PH(L, m+8*p)] = {ve.x, ve.y, vo.x, vo.y};
  }
}
__device__ inline void row_s1_i(float4* S4, const cplx* TW, int L, int m){
  cplx xe[8], xo[8];
  #pragma unroll
  for (int p=0;p<8;p++){
    float4 v = S4[PH(L, m+8*p)];
    xe[p]={v.x,v.y}; xo[p]={v.z,v.w};
  }
  cplx A[8]; twchainA(TW, 2*m, A);
  #pragma unroll
  for (int p=0;p<8;p++){
    cplx B = cmul(A[p], W128BR[p]);
    xe[p] = cmulc(xe[p], A[p]);
    xo[p] = cmulc(xo[p], B);
  }
  bf8_inv(xe); bf8_inv(xo);
  #pragma unroll
  for (int t=0;t<4;t++)
    S4[PH(L, m+8*t)] = {xe[t].x, xe[t].y, xo[t].x, xo[t].y};
}
// row s2: L = 8w + (lane&7), jb = lane>>3 (L varies at fixed k -> conflict-free)
__device__ inline void row_s2_f(float4* S4, int L, int jb){
  cplx z[16];
  #pragma unroll
  for (int k=0;k<8;k++){
    float4 v = S4[PH(L, jb*8+k)];
    z[2*k]={v.x,v.y}; z[2*k+1]={v.z,v.w};
  }
  fft16_fwd(z);
  #pragma unroll
  for (int k=0;k<8;k++)
    S4[PH(L, jb*8+k)] = {z[2*k].x, z[2*k].y, z[2*k+1].x, z[2*k+1].y};
}
__device__ inline void row_s2_i(float4* S4, int L, int jb){
  cplx z[16];
  #pragma unroll
  for (int k=0;k<8;k++){
    float4 v = S4[PH(L, jb*8+k)];
    z[2*k]={v.x,v.y}; z[2*k+1]={v.z,v.w};
  }
  fft16_inv(z);
  #pragma unroll
  for (int k=0;k<8;k++)
    S4[PH(L, jb*8+k)] = {z[2*k].x, z[2*k].y, z[2*k+1].x, z[2*k+1].y};
}
template<bool ZT>
__device__ inline void col_s1_f(float4* S4, const cplx* TW, int yj, int sc){
  cplx xe[8], xo[8];
  #pragma unroll
  for (int t=0; t<(ZT?4:8); t++){
    float4 v = S4[PH(yj+16*t, sc)];
    xe[t]={v.x,v.y}; xo[t]={v.z,v.w};
  }
  if (ZT){ bf8_fwd_z(xe); bf8_fwd_z(xo); } else { bf8_fwd(xe); bf8_fwd(xo); }
  cplx A[8]; twchainA(TW, yj, A);
  #pragma unroll
  for (int p=0;p<8;p++){
    cplx ve = cmul(xe[p], A[p]);
    cplx vo = cmul(xo[p], A[p]);
    S4[PH(yj+16*p, sc)] = {ve.x, ve.y, vo.x, vo.y};
  }
}
__device__ inline void col_s1_i(float4* S4, const cplx* TW, int yj, int sc){
  cplx xe[8], xo[8];
  #pragma unroll
  for (int p=0;p<8;p++){
    float4 v = S4[PH(yj+16*p, sc)];
    xe[p]={v.x,v.y}; xo[p]={v.z,v.w};
  }
  cplx A[8]; twchainA(TW, yj, A);
  #pragma unroll
  for (int p=0;p<8;p++){
    xe[p] = cmulc(xe[p], A[p]);
    xo[p] = cmulc(xo[p], A[p]);
  }
  bf8_inv(xe); bf8_inv(xo);
  #pragma unroll
  for (int t=0;t<4;t++)
    S4[PH(yj+16*t, sc)] = {xe[t].x, xe[t].y, xo[t].x, xo[t].y};
}

// ---------------- wave-shuffle reductions ----------------
__device__ inline float wred(float v){
  #pragma unroll
  for (int o=32;o;o>>=1) v += __shfl_xor(v, o, 64);
  return v;
}
__device__ inline float wredmax(float v){
  #pragma unroll
  for (int o=32;o;o>>=1) v = fmaxf(v, __shfl_xor(v, o, 64));
  return v;
}

__device__ inline cplx wval(int r, int c, int which){
  const int dy = (r<64)? r : r-128;
  const int dx = (c<64)? c : c-128;
  float a, b;
  if (which==0){ a = 1.f-(float)dy; b = 1.f-(float)dx; }
  else         { a = 1.f+(float)dy; b = 1.f+(float)dx; }
  const float den = a*a + b*b;
  if (r==64 || c==64 || den<=0.f) return {0.f,0.f};
  const float inv = 1.f/den;
  return {a*inv, -b*inv};
}

// ---------------- prep: 2 blocks, kernel FFT -> W1/W2 ------------------------
__global__ __launch_bounds__(TPB,4) void prep_kernel(float* __restrict__ W1,
                                                     float* __restrict__ W2){
  __shared__ float4 S4[8192];
  __shared__ cplx TW[128];
  const int tid = threadIdx.x;
  const int wvx = tid >> 6, lane = tid & 63;
  const int which = blockIdx.x;
  if (tid < 128){
    float s, c;
    sincosf(-6.283185307179586f * (float)tid / 128.0f, &s, &c);
    TW[tid] = {c, s};
  }
  for (int s = tid; s < 8192; s += TPB){
    const int y = s>>6, m = s&63;
    const cplx v0 = wval(y, 2*m, which);
    const cplx v1 = wval(y, 2*m+1, which);
    S4[PH(y, m)] = {v0.x, v0.y, v1.x, v1.y};
  }
  __syncthreads();
  { // rows: wave w owns rows 8w..8w+7
    row_s1_f<false>(S4, TW, 8*wvx + (lane>>3), lane&7, 0.0f);
    wsync();
    row_s2_f(S4, 8*wvx + (lane&7), lane>>3);
  }
  __syncthreads();
  { // cols
    const int yj = lane & 15, sc = 4*wvx + (lane>>4);
    col_s1_f<false>(S4, TW, yj, sc);
    wsync();
    cplx* Sc = (cplx*)S4;
    const int c = 8*wvx + (lane&7), r = lane>>3;
    cplx z[16];
    #pragma unroll
    for (int i=0;i<16;i++)
      z[i] = Sc[2*PH(16*r+i, c>>1) + (c&1)];
    fft16_fwd(z);
    cplx* Wo = (cplx*)((which==0)?W1:W2);
    const float scl = 1.0f / 16384.0f;
    #pragma unroll
    for (int i=0;i<16;i++) Wo[(16*r+i)*128 + c] = {z[i].x*scl, z[i].y*scl};
  }
}

// ---------------- conv: blocks 0..255 conv2 (fds), 256..511 conv1 (+lvec/lpt) --------
__global__ __launch_bounds__(TPB,4) void conv_kernel(const float* __restrict__ heat,
                                                     const float* __restrict__ fields,
                                                     const float* __restrict__ W1g,
                                                     const float* __restrict__ W2g,
                                                     const int* __restrict__ ishape,
                                                     float* __restrict__ out,
                                                     float* __restrict__ fds){
  __shared__ float4 S4[8192];
  __shared__ cplx TW[128];
  __shared__ float2 R2A[16];
  __shared__ float4 R4A[16], R4B[16];
  const int tid = threadIdx.x;
  const int wv = tid >> 6, lane = tid & 63;
  const int n = blockIdx.x;
  const bool is2 = (n < 256);
  const int m_img = is2 ? n : (n - 256);
  if (tid < 128){
    float s, c;
    sincosf(-6.283185307179586f * (float)tid / 128.0f, &s, &c);
    TW[tid] = {c, s};
  }
  const float* f = fields + (size_t)m_img * 3 * NPIX;
  const int y = tid >> 4, x4 = (tid & 15) << 2;
  const int i = (y << 6) + x4;
  const int m = (tid & 15) << 1;
  float4 f0h, f1h, f2h;   // hoisted conv1 epilogue operands (in flight across the FFT)
  if (!is2){
    f0h = *(const float4*)(f + i);
    f1h = *(const float4*)(f + NPIX + i);
    f2h = *(const float4*)(f + 2*NPIX + i);
    // conv1 stage: raw diffs into LDS immediately; mean partial stashed; -dm folded into row_s1
    const int bv = m_img >> 4, l = m_img & 15;
    const int j1 = bv*NJ + c_P1[l], j0 = bv*NJ + c_P0[l];
    const float4 a = *(const float4*)(heat + (size_t)j1*NPIX + i);
    const float4 b = *(const float4*)(heat + (size_t)j0*NPIX + i);
    const float d0=a.x-b.x, d1=a.y-b.y, d2=a.z-b.z, d3=a.w-b.w;
    S4[PH(y, m  )] = {d0, 0.f, d1, 0.f};
    S4[PH(y, m+1)] = {d2, 0.f, d3, 0.f};
    const float ps = wred(d0+d1+d2+d3);
    if (lane == 0) R2A[wv].x = ps;
  } else {
    // conv2 stage: ch1->re, ch0->im; std partials stashed (sf used only in epilogue)
    const float4 A = *(const float4*)(f + NPIX + i);
    const float4 B = *(const float4*)(f + i);
    const float4 C = *(const float4*)(f + 2*NPIX + i);
    S4[PH(y, m  )] = {A.x, B.x, A.y, B.y};
    S4[PH(y, m+1)] = {A.z, B.z, A.w, B.w};
    float s1 = A.x+A.y+A.z+A.w + B.x+B.y+B.z+B.w + C.x+C.y+C.z+C.w;
    float s2 = A.x*A.x+A.y*A.y+A.z*A.z+A.w*A.w
             + B.x*B.x+B.y*B.y+B.z*B.z+B.w*B.w
             + C.x*C.x+C.y*C.y+C.z*C.z+C.w*C.w;
    const float2 pr = {wred(s1), wred(s2)};
    if (lane == 0) R2A[wv] = pr;
  }
  __syncthreads();                       // B1 (staging + stat partials)
  float dm = 0.0f, sf_loc = 0.0f;
  if (!is2){
    float S = 0.f;
    #pragma unroll
    for (int k2=0;k2<16;k2++) S += R2A[k2].x;
    dm = S * (1.0f/4096.0f);
  } else {
    float S1 = 0.f, S2 = 0.f;
    #pragma unroll
    for (int k2=0;k2<16;k2++){ S1 += R2A[k2].x; S2 += R2A[k2].y; }
    const float var = (S2 - S1*S1/12288.0f) / 12287.0f;
    const float sd = sqrtf(fmaxf(var, 0.0f));
    sf_loc = sd / (sd + 1e-6f);
  }
  // ROWS FWD: waves 0..7 own rows 8w..8w+7 (wave-local); -dm applied on load
  if (wv < 8){
    row_s1_f<true>(S4, TW, 8*wv + (lane>>3), lane&7, dm);
    wsync();
    row_s2_f(S4, 8*wv + (lane&7), lane>>3);
  }
  __syncthreads();                       // B2 (transpose)
  // COLS: wave w owns slot-cols 4w..4w+3 (wave-local full chain)
  {
    const cplx* Wg = (const cplx*)(is2 ? W2g : W1g);
    const int c = 8*wv + (lane&7), r = lane>>3;
    cplx wvv[16];
    #pragma unroll
    for (int k=0;k<16;k++) wvv[k] = Wg[(16*r+k)*128 + c];   // prefetch
    const int yj = lane & 15, sc = 4*wv + (lane>>4);
    col_s1_f<true>(S4, TW, yj, sc);
    wsync();
    {
      cplx* Sc = (cplx*)S4;
      cplx z[16];
      int ad[16];
      #pragma unroll
      for (int k=0;k<16;k++){
        ad[k] = 2*PH(16*r+k, c>>1) + (c&1);
        z[k] = Sc[ad[k]];
      }
      fft16_fwd(z);
      #pragma unroll
      for (int k=0;k<16;k++) z[k] = cmul(z[k], wvv[k]);
      fft16_inv(z);
      #pragma unroll
      for (int k=0;k<16;k++) Sc[ad[k]] = z[k];
    }
    wsync();
    col_s1_i(S4, TW, yj, sc);
  }
  __syncthreads();                       // B3
  // ROWS INV: waves 0..7
  if (wv < 8){
    row_s2_i(S4, 8*wv + (lane&7), lane>>3);
    wsync();
    row_s1_i(S4, TW, 8*wv + (lane>>3), lane&7);
  }
  __syncthreads();                       // B4
  // epilogue
  const float4 va = S4[PH(y, m)];
  const float4 vb = S4[PH(y, m+1)];
  if (!is2){
    float* o = out + O_FN + (size_t)m_img * 3 * NPIX;
    const float c0[4] = {-va.y, -va.w, -vb.y, -vb.w};
    const float c1[4] = { va.x,  va.z,  vb.x,  vb.z};
    const float f0a[4] = {f0h.x,f0h.y,f0h.z,f0h.w};
    const float f1a[4] = {f1h.x,f1h.y,f1h.z,f1h.w};
    const float f2a[4] = {f2h.x,f2h.y,f2h.z,f2h.w};
    float o0[4], o1[4], o2[4], fn[4];
    float a0 = 0.f, a1 = 0.f, a2 = 0.f;
    #pragma unroll
    for (int j=0;j<4;j++){
      const float cf = fmaxf(0.f, c0[j]*f0a[j] + c1[j]*f1a[j]);
      o0[j] = f0a[j]*cf; o1[j] = f1a[j]*cf; o2[j] = f2a[j]*cf;
      const float nn = sqrtf(f0a[j]*f0a[j] + f1a[j]*f1a[j] + f2a[j]*f2a[j]);
      fn[j] = nn;
      a0 += nn*f0a[j]; a1 += nn*f1a[j]; a2 += nn*f2a[j];
    }
    *(float4*)(o + i)          = {o0[0],o0[1],o0[2],o0[3]};
    *(float4*)(o + NPIX + i)   = {o1[0],o1[1],o1[2],o1[3]};
    *(float4*)(o + 2*NPIX + i) = {o2[0],o2[1],o2[2],o2[3]};
    // lvecs / lpts: single-barrier combine (per-wave max + exp rescale at tid0)
    float mx = fmaxf(fmaxf(fn[0],fn[1]), fmaxf(fn[2],fn[3]));
    const float mxw = wredmax(mx);
    float Sm = 0.f, Sx = 0.f, Sy = 0.f;
    #pragma unroll
    for (int j=0;j<4;j++){
      const float e = expf(kBeta * (fn[j] - mxw));
      Sm += e; Sx += e * (float)y; Sy += e * (float)(x4 + j);
    }
    const float4 p1 = {wred(a0), wred(a1), wred(a2), mxw};
    const float4 p2 = {wred(Sm), wred(Sx), wred(Sy), 0.f};
    if (lane == 0){ R4A[wv] = p1; R4B[wv] = p2; }
    __syncthreads();                     // B5
    if (tid == 0){
      float MX = -1e30f;
      #pragma unroll
      for (int k2=0;k2<16;k2++) MX = fmaxf(MX, R4A[k2].w);
      float A0=0.f, A1=0.f, A2=0.f, SM=0.f, SX=0.f, SY=0.f;
      #pragma unroll
      for (int k2=0;k2<16;k2++){
        const float4 q = R4A[k2], p = R4B[k2];
        A0 += q.x; A1 += q.y; A2 += q.z;
        const float rs = expf(kBeta * (q.w - MX));
        SM += p.x*rs; SX += p.y*rs; SY += p.z*rs;
      }
      float nrm = sqrtf(A0*A0 + A1*A1 + A2*A2);
      nrm = fmaxf(nrm, 1e-12f);
      out[O_CV + m_img*3 + 0] = A0/nrm;
      out[O_CV + m_img*3 + 1] = A1/nrm;
      out[O_CV + m_img*3 + 2] = A2/nrm;
      const float sxs = (float)ishape[1] / 64.0f;
      const float sys = (float)ishape[0] / 64.0f;
      out[O_CP + m_img*2 + 0] = SX/SM * sxs;
      out[O_CP + m_img*2 + 1] = SY/SM * sys;
    }
  } else {
    float* o = fds + (size_t)m_img * NPIX;
    *(float4*)(o + i) = {va.x*sf_loc, va.z*sf_loc, vb.x*sf_loc, vb.z*sf_loc};
  }
}

// ---------------- hms_new + normalize + soft-argmax + kps combine (3 barriers) -----------
__global__ __launch_bounds__(HTPB) void hms_kernel(const float* __restrict__ heat,
                                                   const float* __restrict__ fds,
                                                   const float* __restrict__ confs,
                                                   const int* __restrict__ ishape,
                                                   const float* __restrict__ pth1p,
                                                   const float* __restrict__ pth2p,
                                                   float* __restrict__ out){
  __shared__ float2 H2A[4], H2B[4];
  __shared__ float4 H4A[4], H4B[4];
  const int tid = threadIdx.x;
  const int wv = tid >> 6, lane = tid & 63;
  const int idx = blockIdx.x;           // bv*17 + j
  const int bv = idx / NJ, j = idx % NJ;
  const float4* hp4 = (const float4*)(heat + (size_t)idx * NPIX);
  const int pl = c_proxL[j], dl = c_distL[j];
  const float4* fp4 = (pl >= 0) ? (const float4*)(fds + (size_t)(bv*NL + pl) * NPIX) : nullptr;
  const float4* fd4 = (dl >= 0) ? (const float4*)(fds + (size_t)(bv*NL + dl) * NPIX) : nullptr;
  float ho[16], prod[16];
  float s = 0.0f, s2 = 0.0f;
  #pragma unroll
  for (int i = 0; i < 4; i++){
    const int u = tid + i*HTPB;
    const float4 h4 = hp4[u];
    const float hv[4] = {h4.x, h4.y, h4.z, h4.w};
    float pv[4] = {1.f,1.f,1.f,1.f};
    if (pl >= 0){
      const float4 p4 = fp4[u];
      pv[0] = fmaxf(0.f,-p4.x); pv[1] = fmaxf(0.f,-p4.y);
      pv[2] = fmaxf(0.f,-p4.z); pv[3] = fmaxf(0.f,-p4.w);
    }
    float dv[4] = {1.f,1.f,1.f,1.f};
    if (dl >= 0){
      const float4 d4 = fd4[u];
      dv[0] = fmaxf(0.f,d4.x); dv[1] = fmaxf(0.f,d4.y);
      dv[2] = fmaxf(0.f,d4.z); dv[3] = fmaxf(0.f,d4.w);
    }
    #pragma unroll
    for (int k=0;k<4;k++){
      ho[4*i+k] = hv[k];
      prod[4*i+k] = pv[k]*dv[k];
      s += hv[k]; s2 += hv[k]*hv[k];
    }
  }
  {
    const float2 p = {wred(s), wred(s2)};
    if (lane == 0) H2A[wv] = p;
  }
  __syncthreads();                                   // b1
  float S = 0.f, S2 = 0.f;
  #pragma unroll
  for (int k=0;k<4;k++){ S += H2A[k].x; S2 += H2A[k].y; }
  const float mh = S / 4096.0f;
  const float sdh = sqrtf(fmaxf((S2 - S*mh) / 4095.0f, 0.0f));
  float hn[16];
  float sn = 0.0f, sn2 = 0.0f;
  #pragma unroll
  for (int i = 0; i < 16; i++){
    ho[i] -= mh;
    const float mm = ho[i]*prod[i];
    hn[i] = mm;
    sn += mm; sn2 += mm*mm;
  }
  {
    const float2 p = {wred(sn), wred(sn2)};
    if (lane == 0) H2B[wv] = p;
  }
  __syncthreads();                                   // b2
  float SN = 0.f, SN2 = 0.f;
  #pragma unroll
  for (int k=0;k<4;k++){ SN += H2B[k].x; SN2 += H2B[k].y; }
  const float varn = (SN2 - SN*SN/4096.0f) / 4095.0f;
  const float sdn = sqrtf(fmaxf(varn, 0.0f));
  const float scale = sdh / (sdn + 1e-6f);
  float4* ohm4 = (float4*)(out + O_HM + (size_t)idx * NPIX);
  #pragma unroll
  for (int i = 0; i < 4; i++){
    #pragma unroll
    for (int k=0;k<4;k++) hn[4*i+k] *= scale;
    ohm4[tid + i*HTPB] = {hn[4*i], hn[4*i+1], hn[4*i+2], hn[4*i+3]};
  }
  // softmax (old & new) with per-wave max + rescale combine: 1 barrier
  float mo = -1e30f, mn = -1e30f;
  #pragma unroll
  for (int i = 0; i < 16; i++){ mo = fmaxf(mo, ho[i]); mn = fmaxf(mn, hn[i]); }
  const float mow = wredmax(mo), mnw = wredmax(mn);
  float So = 0.0f, Sxo = 0.0f, Syo = 0.0f;
  float Sn = 0.0f, Sxn = 0.0f, Syn = 0.0f;
  #pragma unroll
  for (int i = 0; i < 16; i++){
    const int px = (tid + (i>>2)*HTPB)*4 + (i&3);
    const float yy = (float)(px >> 6), xx = (float)(px & 63);
    const float eo = expf(kBeta * (ho[i] - mow));
    So += eo; Sxo += eo*yy; Syo += eo*xx;
    const float en = expf(kBeta * (hn[i] - mnw));
    Sn += en; Sxn += en*yy; Syn += en*xx;
  }
  {
    const float4 pa = {wred(So), wred(Sxo), wred(Syo), mow};
    const float4 pb = {wred(Sn), wred(Sxn), wred(Syn), mnw};
    if (lane == 0){ H4A[wv] = pa; H4B[wv] = pb; }
  }
  __syncthreads();                                   // b3
  if (tid == 0){
    float MO = -1e30f, MN = -1e30f;
    #pragma unroll
    for (int k=0;k<4;k++){ MO = fmaxf(MO, H4A[k].w); MN = fmaxf(MN, H4B[k].w); }
    float SO=0.f, SXO=0.f, SYO=0.f, SNN=0.f, SXN=0.f, SYN=0.f;
    #pragma unroll
    for (int k=0;k<4;k++){
      const float4 qa = H4A[k], qb = H4B[k];
      const float ra = expf(kBeta * (qa.w - MO));
      const float rb = expf(kBeta * (qb.w - MN));
      SO += qa.x*ra; SXO += qa.y*ra; SYO += qa.z*ra;
      SNN += qb.x*rb; SXN += qb.y*rb; SYN += qb.z*rb;
    }
    const float sxs = (float)ishape[1] / 64.0f;
    const float sys = (float)ishape[0] / 64.0f;
    const float kxo = SXO/SO * sxs, kyo = SYO/SO * sys;
    float kxn = SXN/SNN * sxs, kyn = SYN/SNN * sys;
    if (kxn != kxn) kxn = kxo;
    if (kyn != kyn) kyn = kyo;
    const float ddx = kxn - kxo, ddy = kyn - kyo;
    const float disp = sqrtf(ddx*ddx + ddy*ddy);
    const float conf = confs[bv*(NL+NJ) + NL + j];
    const bool sel = (conf > pth1p[0]) && (disp < pth2p[0]);
    out[O_KPS + idx*2 + 0] = sel ? kxn : kxo;
    out[O_KPS + idx*2 + 1] = sel ? kyn : kyo;
  }
}

extern "C" void kernel_launch(void* const* d_in, const int* in_sizes, int n_in,
                              void* d_out, int out_size, void* d_ws, size_t ws_size,
                              hipStream_t stream) {
  const float* heat   = (const float*)d_in[0];
  const float* fields = (const float*)d_in[1];
  const int*   ishape = (const int*)d_in[5];
  const float* confs  = (const float*)d_in[6];
  const float* pth1   = (const float*)d_in[9];
  const float* pth2   = (const float*)d_in[10];
  float* out = (float*)d_out;
  float* ws = (float*)d_ws;
  float* fds = ws + W_FDS;
  float* W1  = ws + W_W1;
  float* W2  = ws + W_W2;

  hipLaunchKernelGGL(prep_kernel, dim3(2), dim3(TPB), 0, stream, W1, W2);
  hipLaunchKernelGGL(conv_kernel, dim3(512), dim3(TPB), 0, stream,
                     heat, fields, W1, W2, ishape, out, fds);
  hipLaunchKernelGGL(hms_kernel, dim3(272), dim3(HTPB), 0, stream,
                     heat, fds, confs, ishape, pth1, pth2, out);
}

// Round 9
// 140.697 us; speedup vs baseline: 1.0537x; 1.0537x over previous
//
#include <hip/hip_runtime.h>
#include <math.h>

#define TPB 1024
#define HTPB 256
#define NPIX 4096
#define NJ 17
#define NL 16
static constexpr float kBeta = 100.0f;
static constexpr float S2H = 0.70710678118654752f;

// output layout (floats): kps(544) | comb_v(768) | comb_p(512) | fields_new(3145728) | hms_new(1114112)
#define O_KPS 0
#define O_CV 544
#define O_CP 1312
#define O_FN 1824
#define O_HM 3147552
// workspace layout (floats)
#define W_FDS 0               // 256*4096
#define W_W1 1049376          // 16384 cplx
#define W_W2 1082144          // 16384 cplx

__device__ __constant__ int c_P0[16] = {0,1,2,0,4,5,0,7,8,9,8,11,12,8,14,15};
__device__ __constant__ int c_P1[16] = {1,2,3,4,5,6,7,8,9,10,11,12,13,14,15,16};
__device__ __constant__ int c_proxL[17] = {6,1,2,-1,4,5,-1,7,13,9,-1,11,12,-1,14,15,-1};
__device__ __constant__ int c_distL[17] = {-1,0,1,2,3,4,5,6,7,8,9,10,11,12,13,14,15};

using cplx = float2;
__device__ inline cplx cadd(cplx a, cplx b){ return {a.x+b.x, a.y+b.y}; }
__device__ inline cplx csub(cplx a, cplx b){ return {a.x-b.x, a.y-b.y}; }
__device__ inline cplx cmul(cplx a, cplx w){ return {a.x*w.x - a.y*w.y, a.x*w.y + a.y*w.x}; }
__device__ inline cplx cmulc(cplx a, cplx w){ return {a.x*w.x + a.y*w.y, a.y*w.x - a.x*w.y}; }

// intra-wave LDS sync: wave is lockstep; lgkmcnt(0) drains this wave's own ds ops.
__device__ inline void wsync(){
  asm volatile("s_waitcnt lgkmcnt(0)" ::: "memory");
}

// w_128^{br3(p)} and w_16^{br3(p)}, br3 = {0,4,2,6,1,5,3,7}
__device__ __constant__ float2 W128BR[8] = {
  {1.f,0.f},
  {0.98078528040323044913f,-0.19509032201612826785f},
  {0.99518472667219688624f,-0.09801714032956060199f},
  {0.95694033573220886494f,-0.29028467725446236764f},
  {0.99879545620517239271f,-0.04906767432741801425f},
  {0.97003125319454399260f,-0.24298017990326388995f},
  {0.98917650996478097345f,-0.14673047445536175166f},
  {0.94154406518302077841f,-0.33688985339222005069f}
};
__device__ __constant__ float2 W16BR[8] = {
  {1.f,0.f},
  {0.f,-1.f},
  {0.70710678118654752440f,-0.70710678118654752440f},
  {-0.70710678118654752440f,-0.70710678118654752440f},
  {0.92387953251128675613f,-0.38268343236508977173f},
  {-0.38268343236508977173f,-0.92387953251128675613f},
  {0.38268343236508977173f,-0.92387953251128675613f},
  {-0.92387953251128675613f,-0.38268343236508977173f}
};

// -------- 8-point DFT (radix-2 DIF, output bit-reversed); inverse = exact inverse ----
__device__ inline void bf8_tail(cplx t0, cplx t1, cplx t2, cplx t3,
                                cplx t4, cplx t5, cplx t6, cplx t7, cplx x[8]){
  cplx u0=cadd(t0,t2), u2=csub(t0,t2);
  cplx u1=cadd(t1,t3), d13=csub(t1,t3);
  cplx u3={d13.y,-d13.x};
  cplx u4=cadd(t4,t6), u6=csub(t4,t6);
  cplx u5=cadd(t5,t7), d57=csub(t5,t7);
  cplx u7={d57.y,-d57.x};
  x[0]=cadd(u0,u1); x[1]=csub(u0,u1);
  x[2]=cadd(u2,u3); x[3]=csub(u2,u3);
  x[4]=cadd(u4,u5); x[5]=csub(u4,u5);
  x[6]=cadd(u6,u7); x[7]=csub(u6,u7);
}
__device__ inline void bf8_fwd(cplx x[8]){
  cplx t0=cadd(x[0],x[4]), d4=csub(x[0],x[4]);
  cplx t1=cadd(x[1],x[5]), d5=csub(x[1],x[5]);
  cplx t2=cadd(x[2],x[6]), d6=csub(x[2],x[6]);
  cplx t3=cadd(x[3],x[7]), d7=csub(x[3],x[7]);
  cplx t5={S2H*(d5.x+d5.y), S2H*(d5.y-d5.x)};
  cplx t6={d6.y,-d6.x};
  cplx t7={S2H*(d7.y-d7.x), -S2H*(d7.x+d7.y)};
  bf8_tail(t0,t1,t2,t3,d4,t5,t6,t7,x);
}
__device__ inline void bf8_fwd_z(cplx x[8]){   // x[4..7] == 0 implicitly
  cplx t5={S2H*(x[1].x+x[1].y), S2H*(x[1].y-x[1].x)};
  cplx t6={x[2].y,-x[2].x};
  cplx t7={S2H*(x[3].y-x[3].x), -S2H*(x[3].x+x[3].y)};
  bf8_tail(x[0],x[1],x[2],x[3],x[0],t5,t6,t7,x);
}
__device__ inline void bf8_inv(cplx y[8]){
  cplx u0=cadd(y[0],y[1]), u1=csub(y[0],y[1]);
  cplx u2=cadd(y[2],y[3]), u3=csub(y[2],y[3]);
  cplx u4=cadd(y[4],y[5]), u5=csub(y[4],y[5]);
  cplx u6=cadd(y[6],y[7]), u7=csub(y[6],y[7]);
  cplx t0=cadd(u0,u2), t2=csub(u0,u2);
  cplx iu3={-u3.y,u3.x};
  cplx t1=cadd(u1,iu3), t3=csub(u1,iu3);
  cplx t4=cadd(u4,u6), t6=csub(u4,u6);
  cplx iu7={-u7.y,u7.x};
  cplx t5=cadd(u5,iu7), t7=csub(u5,iu7);
  y[0]=cadd(t0,t4); y[4]=csub(t0,t4);
  cplx w5={S2H*(t5.x-t5.y), S2H*(t5.x+t5.y)};
  y[1]=cadd(t1,w5); y[5]=csub(t1,w5);
  cplx w6={-t6.y,t6.x};
  y[2]=cadd(t2,w6); y[6]=csub(t2,w6);
  cplx w7={-S2H*(t7.x+t7.y), S2H*(t7.x-t7.y)};
  y[3]=cadd(t3,w7); y[7]=csub(t3,w7);
}

// -------- 16-point DFT in registers; inverse = exact inverse ----------------
__device__ inline void fft16_fwd(cplx z[16]){
  cplx e[8], o[8];
  #pragma unroll
  for (int t=0;t<8;t++){ e[t]=z[2*t]; o[t]=z[2*t+1]; }
  bf8_fwd(e); bf8_fwd(o);
  #pragma unroll
  for (int p=0;p<8;p++){
    cplx vo = cmul(o[p], W16BR[p]);
    z[2*p]   = cadd(e[p], vo);
    z[2*p+1] = csub(e[p], vo);
  }
}
__device__ inline void fft16_inv(cplx z[16]){
  cplx e[8], o[8];
  #pragma unroll
  for (int p=0;p<8;p++){
    cplx a=z[2*p], b=z[2*p+1];
    e[p] = cadd(a,b);
    o[p] = cmulc(csub(a,b), W16BR[p]);
  }
  bf8_inv(e); bf8_inv(o);
  #pragma unroll
  for (int t=0;t<8;t++){ z[2*t]=e[t]; z[2*t+1]=o[t]; }
}

// A[p] = w_128^{j*br3(p)} via chain from TW[j]
__device__ inline void twchainA(const cplx* TW, int j, cplx A[8]){
  cplx W1 = TW[j];
  cplx W2 = cmul(W1,W1);
  cplx W4 = cmul(W2,W2);
  cplx W6 = cmul(W4,W2);
  A[0] = {1.f,0.f}; A[1] = W4; A[2] = W2; A[3] = W6;
  A[4] = W1; A[5] = cmul(W4,W1); A[6] = cmul(W2,W1); A[7] = cmul(W6,W1);
}

// physical f4-slot for (row y, slot m). XOR swizzle: conflict-free for all passes.
__device__ inline int PH(int y, int m){
  return (y<<6) | ((m ^ ((y&7)*9) ^ ((y>>3)&7) ^ (((y>>4)&1)<<2)) & 63);
}

// ---------------- wave-local FFT passes -------------------------------------------------
// bias: uniform value subtracted from real parts on load (conv1 mean-centering, folded in)
template<bool ZT>
__device__ inline void row_s1_f(float4* S4, const cplx* TW, int L, int m, float bias){
  cplx xe[8], xo[8];
  #pragma unroll
  for (int t=0; t<(ZT?4:8); t++){
    float4 v = S4[PH(L, m+8*t)];
    xe[t]={v.x-bias,v.y}; xo[t]={v.z-bias,v.w};
  }
  if (ZT){ bf8_fwd_z(xe); bf8_fwd_z(xo); } else { bf8_fwd(xe); bf8_fwd(xo); }
  cplx A[8]; twchainA(TW, 2*m, A);
  #pragma unroll
  for (int p=0;p<8;p++){
    cplx B = cmul(A[p], W128BR[p]);
    cplx ve = cmul(xe[p], A[p]);
    cplx vo = cmul(xo[p], B);
    S4[PH(L, m+8*p)] = {ve.x, ve.y, vo.x, vo.y};
  }
}
__device__ inline void row_s1_i(float4* S4, const cplx* TW, int L, int m){
  cplx xe[8], xo[8];
  #pragma unroll
  for (int p=0;p<8;p++){
    float4 v = S4[PH(L, m+8*p)];
    xe[p]={v.x,v.y}; xo[p]={v.z,v.w};
  }
  cplx A[8]; twchainA(TW, 2*m, A);
  #pragma unroll
  for (int p=0;p<8;p++){
    cplx B = cmul(A[p], W128BR[p]);
    xe[p] = cmulc(xe[p], A[p]);
    xo[p] = cmulc(xo[p], B);
  }
  bf8_inv(xe); bf8_inv(xo);
  #pragma unroll
  for (int t=0;t<4;t++)
    S4[PH(L, m+8*t)] = {xe[t].x, xe[t].y, xo[t].x, xo[t].y};
}
// row s2: L = 8w + (lane&7), jb = lane>>3 (L varies at fixed k -> conflict-free)
__device__ inline void row_s2_f(float4* S4, int L, int jb){
  cplx z[16];
  #pragma unroll
  for (int k=0;k<8;k++){
    float4 v = S4[PH(L, jb*8+k)];
    z[2*k]={v.x,v.y}; z[2*k+1]={v.z,v.w};
  }
  fft16_fwd(z);
  #pragma unroll
  for (int k=0;k<8;k++)
    S4[PH(L, jb*8+k)] = {z[2*k].x, z[2*k].y, z[2*k+1].x, z[2*k+1].y};
}
__device__ inline void row_s2_i(float4* S4, int L, int jb){
  cplx z[16];
  #pragma unroll
  for (int k=0;k<8;k++){
    float4 v = S4[PH(L, jb*8+k)];
    z[2*k]={v.x,v.y}; z[2*k+1]={v.z,v.w};
  }
  fft16_inv(z);
  #pragma unroll
  for (int k=0;k<8;k++)
    S4[PH(L, jb*8+k)] = {z[2*k].x, z[2*k].y, z[2*k+1].x, z[2*k+1].y};
}
template<bool ZT>
__device__ inline void col_s1_f(float4* S4, const cplx* TW, int yj, int sc){
  cplx xe[8], xo[8];
  #pragma unroll
  for (int t=0; t<(ZT?4:8); t++){
    float4 v = S4[PH(yj+16*t, sc)];
    xe[t]={v.x,v.y}; xo[t]={v.z,v.w};
  }
  if (ZT){ bf8_fwd_z(xe); bf8_fwd_z(xo); } else { bf8_fwd(xe); bf8_fwd(xo); }
  cplx A[8]; twchainA(TW, yj, A);
  #pragma unroll
  for (int p=0;p<8;p++){
    cplx ve = cmul(xe[p], A[p]);
    cplx vo = cmul(xo[p], A[p]);
    S4[PH(yj+16*p, sc)] = {ve.x, ve.y, vo.x, vo.y};
  }
}
__device__ inline void col_s1_i(float4* S4, const cplx* TW, int yj, int sc){
  cplx xe[8], xo[8];
  #pragma unroll
  for (int p=0;p<8;p++){
    float4 v = S4[PH(yj+16*p, sc)];
    xe[p]={v.x,v.y}; xo[p]={v.z,v.w};
  }
  cplx A[8]; twchainA(TW, yj, A);
  #pragma unroll
  for (int p=0;p<8;p++){
    xe[p] = cmulc(xe[p], A[p]);
    xo[p] = cmulc(xo[p], A[p]);
  }
  bf8_inv(xe); bf8_inv(xo);
  #pragma unroll
  for (int t=0;t<4;t++)
    S4[PH(yj+16*t, sc)] = {xe[t].x, xe[t].y, xo[t].x, xo[t].y};
}

// ---------------- wave-shuffle reductions ----------------
__device__ inline float wred(float v){
  #pragma unroll
  for (int o=32;o;o>>=1) v += __shfl_xor(v, o, 64);
  return v;
}
__device__ inline float wredmax(float v){
  #pragma unroll
  for (int o=32;o;o>>=1) v = fmaxf(v, __shfl_xor(v, o, 64));
  return v;
}

__device__ inline cplx wval(int r, int c, int which){
  const int dy = (r<64)? r : r-128;
  const int dx = (c<64)? c : c-128;
  float a, b;
  if (which==0){ a = 1.f-(float)dy; b = 1.f-(float)dx; }
  else         { a = 1.f+(float)dy; b = 1.f+(float)dx; }
  const float den = a*a + b*b;
  if (r==64 || c==64 || den<=0.f) return {0.f,0.f};
  const float inv = 1.f/den;
  return {a*inv, -b*inv};
}

// ---------------- prep: 2 blocks, kernel FFT -> W1/W2 ------------------------
__global__ __launch_bounds__(TPB,4) void prep_kernel(float* __restrict__ W1,
                                                     float* __restrict__ W2){
  __shared__ float4 S4[8192];
  __shared__ cplx TW[128];
  const int tid = threadIdx.x;
  const int wvx = tid >> 6, lane = tid & 63;
  const int which = blockIdx.x;
  if (tid < 128){
    float s, c;
    sincosf(-6.283185307179586f * (float)tid / 128.0f, &s, &c);
    TW[tid] = {c, s};
  }
  for (int s = tid; s < 8192; s += TPB){
    const int y = s>>6, m = s&63;
    const cplx v0 = wval(y, 2*m, which);
    const cplx v1 = wval(y, 2*m+1, which);
    S4[PH(y, m)] = {v0.x, v0.y, v1.x, v1.y};
  }
  __syncthreads();
  { // rows: wave w owns rows 8w..8w+7
    row_s1_f<false>(S4, TW, 8*wvx + (lane>>3), lane&7, 0.0f);
    wsync();
    row_s2_f(S4, 8*wvx + (lane&7), lane>>3);
  }
  __syncthreads();
  { // cols
    const int yj = lane & 15, sc = 4*wvx + (lane>>4);
    col_s1_f<false>(S4, TW, yj, sc);
    wsync();
    cplx* Sc = (cplx*)S4;
    const int c = 8*wvx + (lane&7), r = lane>>3;
    cplx z[16];
    #pragma unroll
    for (int i=0;i<16;i++)
      z[i] = Sc[2*PH(16*r+i, c>>1) + (c&1)];
    fft16_fwd(z);
    cplx* Wo = (cplx*)((which==0)?W1:W2);
    const float scl = 1.0f / 16384.0f;
    #pragma unroll
    for (int i=0;i<16;i++) Wo[(16*r+i)*128 + c] = {z[i].x*scl, z[i].y*scl};
  }
}

// ---------------- conv: blocks 0..255 conv2 (fds), 256..511 conv1 (+lvec/lpt) --------
__global__ __launch_bounds__(TPB,4) void conv_kernel(const float* __restrict__ heat,
                                                     const float* __restrict__ fields,
                                                     const float* __restrict__ W1g,
                                                     const float* __restrict__ W2g,
                                                     const int* __restrict__ ishape,
                                                     float* __restrict__ out,
                                                     float* __restrict__ fds){
  __shared__ float4 S4[8192];
  __shared__ cplx TW[128];
  __shared__ float2 R2A[16];
  __shared__ float4 R4A[16], R4B[16];
  const int tid = threadIdx.x;
  const int wv = tid >> 6, lane = tid & 63;
  const int n = blockIdx.x;
  const bool is2 = (n < 256);
  const int m_img = is2 ? n : (n - 256);
  if (tid < 128){
    float s, c;
    sincosf(-6.283185307179586f * (float)tid / 128.0f, &s, &c);
    TW[tid] = {c, s};
  }
  const float* f = fields + (size_t)m_img * 3 * NPIX;
  const int y = tid >> 4, x4 = (tid & 15) << 2;
  const int i = (y << 6) + x4;
  const int m = (tid & 15) << 1;
  if (!is2){
    // conv1 stage: raw diffs into LDS; mean partial stashed; -dm folded into row_s1
    const int bv = m_img >> 4, l = m_img & 15;
    const int j1 = bv*NJ + c_P1[l], j0 = bv*NJ + c_P0[l];
    const float4 a = *(const float4*)(heat + (size_t)j1*NPIX + i);
    const float4 b = *(const float4*)(heat + (size_t)j0*NPIX + i);
    const float d0=a.x-b.x, d1=a.y-b.y, d2=a.z-b.z, d3=a.w-b.w;
    S4[PH(y, m  )] = {d0, 0.f, d1, 0.f};
    S4[PH(y, m+1)] = {d2, 0.f, d3, 0.f};
    const float ps = wred(d0+d1+d2+d3);
    if (lane == 0) R2A[wv].x = ps;
  } else {
    // conv2 stage: ch1->re, ch0->im; std partials stashed (sf used only in epilogue)
    const float4 A = *(const float4*)(f + NPIX + i);
    const float4 B = *(const float4*)(f + i);
    const float4 C = *(const float4*)(f + 2*NPIX + i);
    S4[PH(y, m  )] = {A.x, B.x, A.y, B.y};
    S4[PH(y, m+1)] = {A.z, B.z, A.w, B.w};
    float s1 = A.x+A.y+A.z+A.w + B.x+B.y+B.z+B.w + C.x+C.y+C.z+C.w;
    float s2 = A.x*A.x+A.y*A.y+A.z*A.z+A.w*A.w
             + B.x*B.x+B.y*B.y+B.z*B.z+B.w*B.w
             + C.x*C.x+C.y*C.y+C.z*C.z+C.w*C.w;
    const float2 pr = {wred(s1), wred(s2)};
    if (lane == 0) R2A[wv] = pr;
  }
  __syncthreads();                       // B1 (staging + stat partials)
  float dm = 0.0f, sf_loc = 0.0f;
  if (!is2){
    float S = 0.f;
    #pragma unroll
    for (int k2=0;k2<16;k2++) S += R2A[k2].x;
    dm = S * (1.0f/4096.0f);
  } else {
    float S1 = 0.f, S2 = 0.f;
    #pragma unroll
    for (int k2=0;k2<16;k2++){ S1 += R2A[k2].x; S2 += R2A[k2].y; }
    const float var = (S2 - S1*S1/12288.0f) / 12287.0f;
    const float sd = sqrtf(fmaxf(var, 0.0f));
    sf_loc = sd / (sd + 1e-6f);
  }
  // ROWS FWD: waves 0..7 own rows 8w..8w+7 (wave-local); -dm applied on load
  if (wv < 8){
    row_s1_f<true>(S4, TW, 8*wv + (lane>>3), lane&7, dm);
    wsync();
    row_s2_f(S4, 8*wv + (lane&7), lane>>3);
  }
  __syncthreads();                       // B2 (transpose)
  // COLS: wave w owns slot-cols 4w..4w+3 (wave-local full chain)
  {
    const int yj = lane & 15, sc = 4*wv + (lane>>4);
    col_s1_f<true>(S4, TW, yj, sc);
    wsync();
    {
      // register diet: no ad[] (recompute addresses); W loads issued here with a
      // short live range — they overlap the LDS z-reads, not the whole s1 pass.
      const cplx* Wg = (const cplx*)(is2 ? W2g : W1g);
      const int c = 8*wv + (lane&7), r = lane>>3;
      cplx wvv[16];
      #pragma unroll
      for (int k=0;k<16;k++) wvv[k] = Wg[(16*r+k)*128 + c];
      cplx* Sc = (cplx*)S4;
      cplx z[16];
      #pragma unroll
      for (int k=0;k<16;k++) z[k] = Sc[2*PH(16*r+k, c>>1) + (c&1)];
      fft16_fwd(z);
      #pragma unroll
      for (int k=0;k<16;k++) z[k] = cmul(z[k], wvv[k]);
      fft16_inv(z);
      #pragma unroll
      for (int k=0;k<16;k++) Sc[2*PH(16*r+k, c>>1) + (c&1)] = z[k];
    }
    wsync();
    col_s1_i(S4, TW, yj, sc);
  }
  __syncthreads();                       // B3
  // ROWS INV: waves 0..7
  if (wv < 8){
    row_s2_i(S4, 8*wv + (lane&7), lane>>3);
    wsync();
    row_s1_i(S4, TW, 8*wv + (lane>>3), lane&7);
  }
  __syncthreads();                       // B4
  // epilogue
  const float4 va = S4[PH(y, m)];
  const float4 vb = S4[PH(y, m+1)];
  if (!is2){
    float* o = out + O_FN + (size_t)m_img * 3 * NPIX;
    const float4 f0 = *(const float4*)(f + i);
    const float4 f1 = *(const float4*)(f + NPIX + i);
    const float4 f2 = *(const float4*)(f + 2*NPIX + i);
    const float c0[4] = {-va.y, -va.w, -vb.y, -vb.w};
    const float c1[4] = { va.x,  va.z,  vb.x,  vb.z};
    const float f0a[4] = {f0.x,f0.y,f0.z,f0.w};
    const float f1a[4] = {f1.x,f1.y,f1.z,f1.w};
    const float f2a[4] = {f2.x,f2.y,f2.z,f2.w};
    float o0[4], o1[4], o2[4], fn[4];
    float a0 = 0.f, a1 = 0.f, a2 = 0.f;
    #pragma unroll
    for (int j=0;j<4;j++){
      const float cf = fmaxf(0.f, c0[j]*f0a[j] + c1[j]*f1a[j]);
      o0[j] = f0a[j]*cf; o1[j] = f1a[j]*cf; o2[j] = f2a[j]*cf;
      const float nn = sqrtf(f0a[j]*f0a[j] + f1a[j]*f1a[j] + f2a[j]*f2a[j]);
      fn[j] = nn;
      a0 += nn*f0a[j]; a1 += nn*f1a[j]; a2 += nn*f2a[j];
    }
    *(float4*)(o + i)          = {o0[0],o0[1],o0[2],o0[3]};
    *(float4*)(o + NPIX + i)   = {o1[0],o1[1],o1[2],o1[3]};
    *(float4*)(o + 2*NPIX + i) = {o2[0],o2[1],o2[2],o2[3]};
    // lvecs / lpts: single-barrier combine (per-wave max + exp rescale at tid0)
    float mx = fmaxf(fmaxf(fn[0],fn[1]), fmaxf(fn[2],fn[3]));
    const float mxw = wredmax(mx);
    float Sm = 0.f, Sx = 0.f, Sy = 0.f;
    #pragma unroll
    for (int j=0;j<4;j++){
      const float e = expf(kBeta * (fn[j] - mxw));
      Sm += e; Sx += e * (float)y; Sy += e * (float)(x4 + j);
    }
    const float4 p1 = {wred(a0), wred(a1), wred(a2), mxw};
    const float4 p2 = {wred(Sm), wred(Sx), wred(Sy), 0.f};
    if (lane == 0){ R4A[wv] = p1; R4B[wv] = p2; }
    __syncthreads();                     // B5
    if (tid == 0){
      float MX = -1e30f;
      #pragma unroll
      for (int k2=0;k2<16;k2++) MX = fmaxf(MX, R4A[k2].w);
      float A0=0.f, A1=0.f, A2=0.f, SM=0.f, SX=0.f, SY=0.f;
      #pragma unroll
      for (int k2=0;k2<16;k2++){
        const float4 q = R4A[k2], p = R4B[k2];
        A0 += q.x; A1 += q.y; A2 += q.z;
        const float rs = expf(kBeta * (q.w - MX));
        SM += p.x*rs; SX += p.y*rs; SY += p.z*rs;
      }
      float nrm = sqrtf(A0*A0 + A1*A1 + A2*A2);
      nrm = fmaxf(nrm, 1e-12f);
      out[O_CV + m_img*3 + 0] = A0/nrm;
      out[O_CV + m_img*3 + 1] = A1/nrm;
      out[O_CV + m_img*3 + 2] = A2/nrm;
      const float sxs = (float)ishape[1] / 64.0f;
      const float sys = (float)ishape[0] / 64.0f;
      out[O_CP + m_img*2 + 0] = SX/SM * sxs;
      out[O_CP + m_img*2 + 1] = SY/SM * sys;
    }
  } else {
    float* o = fds + (size_t)m_img * NPIX;
    *(float4*)(o + i) = {va.x*sf_loc, va.z*sf_loc, vb.x*sf_loc, vb.z*sf_loc};
  }
}

// ---------------- hms_new + normalize + soft-argmax + kps combine (3 barriers) -----------
__global__ __launch_bounds__(HTPB) void hms_kernel(const float* __restrict__ heat,
                                                   const float* __restrict__ fds,
                                                   const float* __restrict__ confs,
                                                   const int* __restrict__ ishape,
                                                   const float* __restrict__ pth1p,
                                                   const float* __restrict__ pth2p,
                                                   float* __restrict__ out){
  __shared__ float2 H2A[4], H2B[4];
  __shared__ float4 H4A[4], H4B[4];
  const int tid = threadIdx.x;
  const int wv = tid >> 6, lane = tid & 63;
  const int idx = blockIdx.x;           // bv*17 + j
  const int bv = idx / NJ, j = idx % NJ;
  const float4* hp4 = (const float4*)(heat + (size_t)idx * NPIX);
  const int pl = c_proxL[j], dl = c_distL[j];
  const float4* fp4 = (pl >= 0) ? (const float4*)(fds + (size_t)(bv*NL + pl) * NPIX) : nullptr;
  const float4* fd4 = (dl >= 0) ? (const float4*)(fds + (size_t)(bv*NL + dl) * NPIX) : nullptr;
  float ho[16], prod[16];
  float s = 0.0f, s2 = 0.0f;
  #pragma unroll
  for (int i = 0; i < 4; i++){
    const int u = tid + i*HTPB;
    const float4 h4 = hp4[u];
    const float hv[4] = {h4.x, h4.y, h4.z, h4.w};
    float pv[4] = {1.f,1.f,1.f,1.f};
    if (pl >= 0){
      const float4 p4 = fp4[u];
      pv[0] = fmaxf(0.f,-p4.x); pv[1] = fmaxf(0.f,-p4.y);
      pv[2] = fmaxf(0.f,-p4.z); pv[3] = fmaxf(0.f,-p4.w);
    }
    float dv[4] = {1.f,1.f,1.f,1.f};
    if (dl >= 0){
      const float4 d4 = fd4[u];
      dv[0] = fmaxf(0.f,d4.x); dv[1] = fmaxf(0.f,d4.y);
      dv[2] = fmaxf(0.f,d4.z); dv[3] = fmaxf(0.f,d4.w);
    }
    #pragma unroll
    for (int k=0;k<4;k++){
      ho[4*i+k] = hv[k];
      prod[4*i+k] = pv[k]*dv[k];
      s += hv[k]; s2 += hv[k]*hv[k];
    }
  }
  {
    const float2 p = {wred(s), wred(s2)};
    if (lane == 0) H2A[wv] = p;
  }
  __syncthreads();                                   // b1
  float S = 0.f, S2 = 0.f;
  #pragma unroll
  for (int k=0;k<4;k++){ S += H2A[k].x; S2 += H2A[k].y; }
  const float mh = S / 4096.0f;
  const float sdh = sqrtf(fmaxf((S2 - S*mh) / 4095.0f, 0.0f));
  float hn[16];
  float sn = 0.0f, sn2 = 0.0f;
  #pragma unroll
  for (int i = 0; i < 16; i++){
    ho[i] -= mh;
    const float mm = ho[i]*prod[i];
    hn[i] = mm;
    sn += mm; sn2 += mm*mm;
  }
  {
    const float2 p = {wred(sn), wred(sn2)};
    if (lane == 0) H2B[wv] = p;
  }
  __syncthreads();                                   // b2
  float SN = 0.f, SN2 = 0.f;
  #pragma unroll
  for (int k=0;k<4;k++){ SN += H2B[k].x; SN2 += H2B[k].y; }
  const float varn = (SN2 - SN*SN/4096.0f) / 4095.0f;
  const float sdn = sqrtf(fmaxf(varn, 0.0f));
  const float scale = sdh / (sdn + 1e-6f);
  float4* ohm4 = (float4*)(out + O_HM + (size_t)idx * NPIX);
  #pragma unroll
  for (int i = 0; i < 4; i++){
    #pragma unroll
    for (int k=0;k<4;k++) hn[4*i+k] *= scale;
    ohm4[tid + i*HTPB] = {hn[4*i], hn[4*i+1], hn[4*i+2], hn[4*i+3]};
  }
  // softmax (old & new) with per-wave max + rescale combine: 1 barrier
  float mo = -1e30f, mn = -1e30f;
  #pragma unroll
  for (int i = 0; i < 16; i++){ mo = fmaxf(mo, ho[i]); mn = fmaxf(mn, hn[i]); }
  const float mow = wredmax(mo), mnw = wredmax(mn);
  float So = 0.0f, Sxo = 0.0f, Syo = 0.0f;
  float Sn = 0.0f, Sxn = 0.0f, Syn = 0.0f;
  #pragma unroll
  for (int i = 0; i < 16; i++){
    const int px = (tid + (i>>2)*HTPB)*4 + (i&3);
    const float yy = (float)(px >> 6), xx = (float)(px & 63);
    const float eo = expf(kBeta * (ho[i] - mow));
    So += eo; Sxo += eo*yy; Syo += eo*xx;
    const float en = expf(kBeta * (hn[i] - mnw));
    Sn += en; Sxn += en*yy; Syn += en*xx;
  }
  {
    const float4 pa = {wred(So), wred(Sxo), wred(Syo), mow};
    const float4 pb = {wred(Sn), wred(Sxn), wred(Syn), mnw};
    if (lane == 0){ H4A[wv] = pa; H4B[wv] = pb; }
  }
  __syncthreads();                                   // b3
  if (tid == 0){
    float MO = -1e30f, MN = -1e30f;
    #pragma unroll
    for (int k=0;k<4;k++){ MO = fmaxf(MO, H4A[k].w); MN = fmaxf(MN, H4B[k].w); }
    float SO=0.f, SXO=0.f, SYO=0.f, SNN=0.f, SXN=0.f, SYN=0.f;
    #pragma unroll
    for (int k=0;k<4;k++){
      const float4 qa = H4A[k], qb = H4B[k];
      const float ra = expf(kBeta * (qa.w - MO));
      const float rb = expf(kBeta * (qb.w - MN));
      SO += qa.x*ra; SXO += qa.y*ra; SYO += qa.z*ra;
      SNN += qb.x*rb; SXN += qb.y*rb; SYN += qb.z*rb;
    }
    const float sxs = (float)ishape[1] / 64.0f;
    const float sys = (float)ishape[0] / 64.0f;
    const float kxo = SXO/SO * sxs, kyo = SYO/SO * sys;
    float kxn = SXN/SNN * sxs, kyn = SYN/SNN * sys;
    if (kxn != kxn) kxn = kxo;
    if (kyn != kyn) kyn = kyo;
    const float ddx = kxn - kxo, ddy = kyn - kyo;
    const float disp = sqrtf(ddx*ddx + ddy*ddy);
    const float conf = confs[bv*(NL+NJ) + NL + j];
    const bool sel = (conf > pth1p[0]) && (disp < pth2p[0]);
    out[O_KPS + idx*2 + 0] = sel ? kxn : kxo;
    out[O_KPS + idx*2 + 1] = sel ? kyn : kyo;
  }
}

extern "C" void kernel_launch(void* const* d_in, const int* in_sizes, int n_in,
                              void* d_out, int out_size, void* d_ws, size_t ws_size,
                              hipStream_t stream) {
  const float* heat   = (const float*)d_in[0];
  const float* fields = (const float*)d_in[1];
  const int*   ishape = (const int*)d_in[5];
  const float* confs  = (const float*)d_in[6];
  const float* pth1   = (const float*)d_in[9];
  const float* pth2   = (const float*)d_in[10];
  float* out = (float*)d_out;
  float* ws = (float*)d_ws;
  float* fds = ws + W_FDS;
  float* W1  = ws + W_W1;
  float* W2  = ws + W_W2;

  hipLaunchKernelGGL(prep_kernel, dim3(2), dim3(TPB), 0, stream, W1, W2);
  hipLaunchKernelGGL(conv_kernel, dim3(512), dim3(TPB), 0, stream,
                     heat, fields, W1, W2, ishape, out, fds);
  hipLaunchKernelGGL(hms_kernel, dim3(272), dim3(HTPB), 0, stream,
                     heat, fds, confs, ishape, pth1, pth2, out);
}